// Round 10
// baseline (225.319 us; speedup 1.0000x reference)
//
#include <hip/hip_runtime.h>
#include <hip/hip_bf16.h>

#define NTOK 8192   // B*S
#define DDIM 1024
#define NEXP 32
#define HDIM 128
#define TOPK 4

typedef __attribute__((ext_vector_type(8))) short bf16x8;
typedef __attribute__((ext_vector_type(4))) float f32x4;

typedef unsigned int uint_g __attribute__((address_space(1)));
typedef unsigned int uint_l __attribute__((address_space(3)));

// async 16B/lane global->LDS; LDS dest = wave-uniform base + lane*16.
// Global source may be per-lane (gather is legal; only the LDS side is constrained).
__device__ __forceinline__ void async_cp16(const void* g, void* l) {
    __builtin_amdgcn_global_load_lds((const uint_g*)g, (uint_l*)l, 16, 0, 0);
}

__device__ inline unsigned short f2bf(float f) {
    unsigned int u = __builtin_bit_cast(unsigned int, f);
    unsigned int r = (u + 0x7fffu + ((u >> 16) & 1u)) >> 16;   // RNE
    return (unsigned short)r;
}
__device__ inline float bf2f(unsigned short s) {
    unsigned int u = ((unsigned int)s) << 16;
    return __builtin_bit_cast(float, u);
}

// ---------------- Kernel P: K/V -> bf16 MFMA-B layout; X -> bf16 row-major ----------------
__global__ __launch_bounds__(256) void prep_weights(
    const float* __restrict__ x,
    const float* __restrict__ keys, const float* __restrict__ values,
    unsigned short* __restrict__ Kb, unsigned short* __restrict__ Vb,
    unsigned short* __restrict__ Xb)
{
    int idx = blockIdx.x * 256 + threadIdx.x;
    unsigned short o[8];
    if (idx < NEXP * 128 * 128) {            // keys: (e, k0 [128], n [128])
        int n = idx & 127, k0 = (idx >> 7) & 127, e = idx >> 14;
        const float* s = keys + ((size_t)e * DDIM + k0 * 8) * HDIM + n;
        #pragma unroll
        for (int j = 0; j < 8; ++j) o[j] = f2bf(s[(size_t)j * HDIM]);
        *(uint4*)&Kb[(size_t)idx * 8] = *(uint4*)o;
    } else if (idx < 2 * NEXP * 128 * 128) { // values: (e, k0 [16], n [1024])
        idx -= NEXP * 128 * 128;
        int n = idx & 1023, k0 = (idx >> 10) & 15, e = idx >> 14;
        const float* s = values + ((size_t)e * HDIM + k0 * 8) * DDIM + n;
        #pragma unroll
        for (int j = 0; j < 8; ++j) o[j] = f2bf(s[(size_t)j * DDIM]);
        *(uint4*)&Vb[(size_t)idx * 8] = *(uint4*)o;
    } else {                                 // x: 8 contiguous elements / thread
        idx -= 2 * NEXP * 128 * 128;
        const float* s = x + (size_t)idx * 8;
        #pragma unroll
        for (int j = 0; j < 8; ++j) o[j] = f2bf(s[j]);
        *(uint4*)&Xb[(size_t)idx * 8] = *(uint4*)o;
    }
}

// ---------------- Kernel G1: gating partial logits (fp32, deterministic) ----------------
__global__ __launch_bounds__(256) void gate_partial(
    const float* __restrict__ x, const float* __restrict__ es,
    float* __restrict__ gpart)               // [4][NTOK][32]
{
    const int n0    = blockIdx.x * 16;
    const int dbase = blockIdx.y * 256;
    const int tid   = threadIdx.x;

    __shared__ float smem[4608];             // staging tiles, reused as Lp
    float* Xt  = smem;                       // [d][tok] stride 36
    float* Est = smem + 64 * 36;             // [d][e]   stride 36

    const int t4  = (tid & 3) * 4;
    const int e4  = ((tid >> 2) & 7) * 4;
    const int rep = tid >> 5;

    const int xr = tid & 15, xc4 = (tid >> 4) * 4;
    const int er = tid & 31, ec8 = (tid >> 5) * 8;

    float acc[4][4] = {};

    for (int dc = dbase; dc < dbase + 256; dc += 64) {
        __syncthreads();
        {
            float4 v = *(const float4*)&x[(size_t)(n0 + xr) * DDIM + dc + xc4];
            Xt[(xc4 + 0) * 36 + xr] = v.x; Xt[(xc4 + 1) * 36 + xr] = v.y;
            Xt[(xc4 + 2) * 36 + xr] = v.z; Xt[(xc4 + 3) * 36 + xr] = v.w;
        }
        #pragma unroll
        for (int i = 0; i < 2; ++i) {
            float4 v = *(const float4*)&es[(size_t)er * DDIM + dc + ec8 + i * 4];
            Est[(ec8 + i * 4 + 0) * 36 + er] = v.x;
            Est[(ec8 + i * 4 + 1) * 36 + er] = v.y;
            Est[(ec8 + i * 4 + 2) * 36 + er] = v.z;
            Est[(ec8 + i * 4 + 3) * 36 + er] = v.w;
        }
        __syncthreads();

        #pragma unroll
        for (int s = 0; s < 8; ++s) {
            int d = s * 8 + rep;
            float4 xv = *(const float4*)&Xt[d * 36 + t4];
            float4 ev = *(const float4*)&Est[d * 36 + e4];
            const float xa[4] = {xv.x, xv.y, xv.z, xv.w};
            const float ea[4] = {ev.x, ev.y, ev.z, ev.w};
            #pragma unroll
            for (int i = 0; i < 4; ++i)
                #pragma unroll
                for (int j = 0; j < 4; ++j)
                    acc[i][j] = fmaf(xa[i], ea[j], acc[i][j]);
        }
    }

    __syncthreads();
    float* Lp = smem;                         // [rep 8][tok 16][e 33]
    #pragma unroll
    for (int i = 0; i < 4; ++i)
        #pragma unroll
        for (int j = 0; j < 4; ++j)
            Lp[(rep * 16 + t4 + i) * 33 + e4 + j] = acc[i][j];
    __syncthreads();

    for (int p = tid; p < 16 * 32; p += 256) {
        int tok = p >> 5, e = p & 31;
        float s = 0.f;
        #pragma unroll
        for (int r = 0; r < 8; ++r) s += Lp[(r * 16 + tok) * 33 + e];
        gpart[((size_t)blockIdx.y * NTOK + n0 + tok) * NEXP + e] = s;
    }
}

// ---------------- Kernel G2: sum partials, top-4 (registers), scatter ----------------
__global__ __launch_bounds__(256) void topk_scatter(
    const float* __restrict__ gpart,
    int* __restrict__ cnt, int* __restrict__ tok_list, float* __restrict__ gates)
{
    const int tid = threadIdx.x;
    const int n   = blockIdx.x * 256 + tid;

    __shared__ int hist[NEXP];
    __shared__ int bbase[NEXP];
    if (tid < NEXP) hist[tid] = 0;

    float lg[NEXP];
    #pragma unroll
    for (int i = 0; i < 8; ++i) {
        float4 v = *(const float4*)&gpart[(size_t)n * NEXP + i * 4];
        lg[i*4+0] = v.x; lg[i*4+1] = v.y; lg[i*4+2] = v.z; lg[i*4+3] = v.w;
    }
    #pragma unroll
    for (int j = 1; j < 4; ++j)
        #pragma unroll
        for (int i = 0; i < 8; ++i) {
            float4 v = *(const float4*)&gpart[((size_t)j * NTOK + n) * NEXP + i * 4];
            lg[i*4+0] += v.x; lg[i*4+1] += v.y; lg[i*4+2] += v.z; lg[i*4+3] += v.w;
        }

    int sel[TOPK]; float sv[TOPK];
    #pragma unroll
    for (int j = 0; j < TOPK; ++j) {
        float bv = -3.0e38f; int bi = 0;
        #pragma unroll
        for (int e = 0; e < NEXP; ++e) {
            bool taken = false;
            #pragma unroll
            for (int q = 0; q < j; ++q) taken = taken || (sel[q] == e);
            float v = taken ? -3.0e38f : lg[e];
            if (v > bv) { bv = v; bi = e; }   // strict >: lowest idx wins ties
        }
        sel[j] = bi; sv[j] = bv;
    }

    __syncthreads();
    int lpos[TOPK];
    #pragma unroll
    for (int j = 0; j < TOPK; ++j) {
        gates[n * TOPK + j] = 1.f / (1.f + expf(-sv[j]));
        lpos[j] = atomicAdd(&hist[sel[j]], 1);
    }
    __syncthreads();
    if (tid < NEXP) bbase[tid] = atomicAdd(&cnt[tid], hist[tid]);
    __syncthreads();
    #pragma unroll
    for (int j = 0; j < TOPK; ++j)
        tok_list[(size_t)sel[j] * NTOK + bbase[sel[j]] + lpos[j]] = n * TOPK + j;
}

// ---------------- Kernel F: fused expert FFN ----------------
// block = (expert, 32-slot tile).  Phase A: H = relu(X@K_e)*g into LDS (row-major,
// pad 136).  Phase B: Ob[slot] = H @ V_e, V streamed through the same 16 KB buffer.
// ~29.6 KB LDS -> 5 blocks/CU; co-resident blocks sit in different phases (overlap).
__global__ __launch_bounds__(256) void ffn_fused(
    const unsigned short* __restrict__ Xb,   // [N][1024] bf16
    const unsigned short* __restrict__ Kb,   // [E][128][128][8]
    const unsigned short* __restrict__ Vb,   // [E][16][1024][8]
    const int* __restrict__ cnt, const int* __restrict__ tok_list,
    const float* __restrict__ gates,
    unsigned short* __restrict__ Ob)         // [N*4][1024] bf16
{
    const int e = blockIdx.y, tile = blockIdx.x;
    const int c = cnt[e], base = tile * 32;
    if (base >= c) return;
    const int nt   = min(32, c - base);
    const int tid  = threadIdx.x, wave = tid >> 6, lane = tid & 63;
    const int lm   = lane & 15, quad = lane >> 4;
    const int r2   = (wave >> 1) * 16;       // 16-row half of the 32-slot tile
    const int c2   = (wave & 1) * 64;        // phase A: 64-col half of 128
    const int cw   = (wave & 1) * 32;        // phase B: 32-col half of 64

    __shared__ __align__(16) unsigned short KV[8192];     // 16 KB: Ks[8][128][8] | Vs[16][64][8]
    __shared__ __align__(16) unsigned short Xs[2048];     //  4 KB: [k0 8][m 32][8]
    __shared__ __align__(16) unsigned short Hs[32 * 136]; // 8.7 KB row-major, pad 136
    __shared__ int slot[32]; __shared__ int gtok[32]; __shared__ float gs[32];

    if (tid < 32) {
        if (tid < nt) {
            int v = tok_list[(size_t)e * NTOK + base + tid];
            slot[tid] = v; gtok[tid] = v >> 2; gs[tid] = gates[v];
        } else { slot[tid] = -1; gtok[tid] = 0; gs[tid] = 0.f; }
    }
    __syncthreads();

    const unsigned short* Ke   = Kb + (size_t)e * 131072;
    const unsigned short* Ve   = Vb + (size_t)e * 131072;
    const unsigned short* xrow = Xb + (size_t)gtok[lane & 31] * DDIM + (lane >> 5) * 8;

    // ---------------- phase A: H[32][128] = X_tile @ K_e ----------------
    f32x4 acc[4];
    #pragma unroll
    for (int j = 0; j < 4; ++j) acc[j] = (f32x4){0.f, 0.f, 0.f, 0.f};

    auto stageA = [&](int t) {
        int dc = t * 64;
        #pragma unroll
        for (int i = 0; i < 4; ++i) {          // K: 16 x 1KB pieces, 4/wave
            int p = wave * 4 + i;
            async_cp16(Ke + ((size_t)(dc / 8 + (p >> 1)) * 128 + (p & 1) * 64 + lane) * 8,
                       &KV[p * 512]);
        }
        if (wave == 0) {                        // X: 4 x 1KB pieces (row gather)
            #pragma unroll
            for (int p = 0; p < 4; ++p)
                async_cp16(xrow + dc + p * 16, &Xs[p * 512]);
        }
    };

    stageA(0);
    __syncthreads();                           // drain

    for (int t = 0; t < 16; ++t) {
        #pragma unroll
        for (int ks = 0; ks < 2; ++ks) {
            int k0 = ks * 4 + quad;
            bf16x8 a = *(const bf16x8*)&Xs[(k0 * 32 + r2 + lm) * 8];
            #pragma unroll
            for (int tj = 0; tj < 4; ++tj) {
                bf16x8 bb = *(const bf16x8*)&KV[(k0 * 128 + c2 + tj * 16 + lm) * 8];
                acc[tj] = __builtin_amdgcn_mfma_f32_16x16x32_bf16(a, bb, acc[tj], 0, 0, 0);
            }
        }
        if (t < 15) {
            __syncthreads();                   // all reads of chunk t done
            stageA(t + 1);
            __syncthreads();                   // drain chunk t+1
        }
    }

    // epilogue A: relu * gate -> Hs (row-major [m][136])
    #pragma unroll
    for (int reg = 0; reg < 4; ++reg) {
        int m = r2 + quad * 4 + reg;
        float g = gs[m];
        #pragma unroll
        for (int tj = 0; tj < 4; ++tj)
            Hs[m * 136 + c2 + tj * 16 + lm] = f2bf(fmaxf(acc[tj][reg], 0.f) * g);
    }
    __syncthreads();                           // Hs complete; KV reads of phase A done

    // ---------------- phase B: Ob = H @ V_e ----------------
    auto stageV = [&](int cc) {
        #pragma unroll
        for (int i = 0; i < 4; ++i) {          // V: 16 x 1KB pieces, 4/wave
            int p = wave * 4 + i;
            async_cp16(Ve + ((size_t)p * 1024 + cc * 64 + lane) * 8, &KV[p * 512]);
        }
    };

    stageV(0);
    __syncthreads();                           // drain

    for (int cc = 0; cc < 16; ++cc) {
        f32x4 acc2[2];
        acc2[0] = (f32x4){0.f, 0.f, 0.f, 0.f};
        acc2[1] = (f32x4){0.f, 0.f, 0.f, 0.f};

        #pragma unroll
        for (int ks = 0; ks < 4; ++ks) {
            int k0 = ks * 4 + quad;
            bf16x8 a = *(const bf16x8*)&Hs[(r2 + lm) * 136 + k0 * 8];
            #pragma unroll
            for (int tj = 0; tj < 2; ++tj) {
                bf16x8 bb = *(const bf16x8*)&KV[(k0 * 64 + cw + tj * 16 + lm) * 8];
                acc2[tj] = __builtin_amdgcn_mfma_f32_16x16x32_bf16(a, bb, acc2[tj], 0, 0, 0);
            }
        }

        #pragma unroll
        for (int reg = 0; reg < 4; ++reg) {
            int m = r2 + quad * 4 + reg;
            int s = slot[m];
            if (s >= 0) {
                unsigned short* op = Ob + (size_t)s * DDIM + cc * 64 + cw + lm;
                op[0]  = f2bf(acc2[0][reg]);
                op[16] = f2bf(acc2[1][reg]);
            }
        }

        if (cc < 15) {
            __syncthreads();                   // Vs reads done
            stageV(cc + 1);
            __syncthreads();                   // drain
        }
    }
}

// ---------------- Kernel R: out[n] = sum_j Ob[4n+j]  (bf16 -> fp32) ----------------
__global__ __launch_bounds__(256) void reduce_out(
    const unsigned short* __restrict__ Ob, float* __restrict__ out)
{
    const int tid = threadIdx.x;
    const int n   = blockIdx.x * 2 + (tid >> 7);
    const int cc  = (tid & 127) * 8;

    float s[8] = {};
    #pragma unroll
    for (int j = 0; j < 4; ++j) {
        uint4 v = *(const uint4*)&Ob[((size_t)n * 4 + j) * DDIM + cc];
        const unsigned int w[4] = {v.x, v.y, v.z, v.w};
        #pragma unroll
        for (int q = 0; q < 4; ++q) {
            s[q * 2 + 0] += bf2f((unsigned short)(w[q] & 0xffff));
            s[q * 2 + 1] += bf2f((unsigned short)(w[q] >> 16));
        }
    }
    float4 o0 = {s[0], s[1], s[2], s[3]};
    float4 o1 = {s[4], s[5], s[6], s[7]};
    *(float4*)&out[(size_t)n * DDIM + cc]     = o0;
    *(float4*)&out[(size_t)n * DDIM + cc + 4] = o1;
}

extern "C" void kernel_launch(void* const* d_in, const int* in_sizes, int n_in,
                              void* d_out, int out_size, void* d_ws, size_t ws_size,
                              hipStream_t stream) {
    const float* x      = (const float*)d_in[0];
    const float* es     = (const float*)d_in[1];
    const float* keys   = (const float*)d_in[2];
    const float* values = (const float*)d_in[3];
    float* out          = (float*)d_out;

    // workspace layout (~105 MB); Xb is now a SEPARATE buffer (fused kernel would
    // race if Xb overlaid Ob: phase-B writes alias rows phase-A still reads)
    char* w = (char*)d_ws;
    int*   cnt      = (int*)w;               w += 256;
    int*   tok_list = (int*)w;               w += (size_t)NEXP * NTOK * sizeof(int);    // 1 MB
    float* gates    = (float*)w;             w += (size_t)NTOK * TOPK * sizeof(float);  // 128 KB
    float* gpart    = (float*)w;             w += (size_t)4 * NTOK * NEXP * sizeof(float); // 4 MB
    unsigned short* Kb = (unsigned short*)w; w += (size_t)NEXP * 128 * 128 * 8 * 2;     // 8 MB
    unsigned short* Vb = (unsigned short*)w; w += (size_t)NEXP * 16 * 1024 * 8 * 2;     // 8 MB
    unsigned short* Xb = (unsigned short*)w; w += (size_t)NTOK * DDIM * 2;              // 16.8 MB
    unsigned short* Ob = (unsigned short*)w;                                            // 67 MB

    hipMemsetAsync(cnt, 0, NEXP * sizeof(int), stream);

    prep_weights<<<8192, 256, 0, stream>>>(x, keys, values, Kb, Vb, Xb);
    gate_partial<<<dim3(NTOK / 16, 4), 256, 0, stream>>>(x, es, gpart);
    topk_scatter<<<NTOK / 256, 256, 0, stream>>>(gpart, cnt, tok_list, gates);

    ffn_fused<<<dim3(128, NEXP), 256, 0, stream>>>(Xb, Kb, Vb, cnt, tok_list, gates, Ob);
    reduce_out<<<NTOK / 2, 256, 0, stream>>>(Ob, out);
}

// Round 11
// 204.032 us; speedup vs baseline: 1.1043x; 1.1043x over previous
//
#include <hip/hip_runtime.h>
#include <hip/hip_bf16.h>

#define NTOK 8192   // B*S
#define DDIM 1024
#define NEXP 32
#define HDIM 128
#define TOPK 4

typedef __attribute__((ext_vector_type(8))) short bf16x8;
typedef __attribute__((ext_vector_type(4))) float f32x4;

typedef unsigned int uint_g __attribute__((address_space(1)));
typedef unsigned int uint_l __attribute__((address_space(3)));

// async 16B/lane global->LDS; LDS dest = wave-uniform base + lane*16.
// Global source may be per-lane (gather is legal; only the LDS side is constrained).
__device__ __forceinline__ void async_cp16(const void* g, void* l) {
    __builtin_amdgcn_global_load_lds((const uint_g*)g, (uint_l*)l, 16, 0, 0);
}

__device__ inline unsigned short f2bf(float f) {
    unsigned int u = __builtin_bit_cast(unsigned int, f);
    unsigned int r = (u + 0x7fffu + ((u >> 16) & 1u)) >> 16;   // RNE
    return (unsigned short)r;
}
__device__ inline float bf2f(unsigned short s) {
    unsigned int u = ((unsigned int)s) << 16;
    return __builtin_bit_cast(float, u);
}

// ---------------- Kernel P: K/V -> bf16 MFMA-B layout; X -> bf16 row-major ----------------
__global__ __launch_bounds__(256) void prep_weights(
    const float* __restrict__ x,
    const float* __restrict__ keys, const float* __restrict__ values,
    unsigned short* __restrict__ Kb, unsigned short* __restrict__ Vb,
    unsigned short* __restrict__ Xb)
{
    int idx = blockIdx.x * 256 + threadIdx.x;
    unsigned short o[8];
    if (idx < NEXP * 128 * 128) {            // keys: (e, k0 [128], n [128])
        int n = idx & 127, k0 = (idx >> 7) & 127, e = idx >> 14;
        const float* s = keys + ((size_t)e * DDIM + k0 * 8) * HDIM + n;
        #pragma unroll
        for (int j = 0; j < 8; ++j) o[j] = f2bf(s[(size_t)j * HDIM]);
        *(uint4*)&Kb[(size_t)idx * 8] = *(uint4*)o;
    } else if (idx < 2 * NEXP * 128 * 128) { // values: (e, k0 [16], n [1024])
        idx -= NEXP * 128 * 128;
        int n = idx & 1023, k0 = (idx >> 10) & 15, e = idx >> 14;
        const float* s = values + ((size_t)e * HDIM + k0 * 8) * DDIM + n;
        #pragma unroll
        for (int j = 0; j < 8; ++j) o[j] = f2bf(s[(size_t)j * DDIM]);
        *(uint4*)&Vb[(size_t)idx * 8] = *(uint4*)o;
    } else {                                 // x: 8 contiguous elements / thread
        idx -= 2 * NEXP * 128 * 128;
        const float* s = x + (size_t)idx * 8;
        #pragma unroll
        for (int j = 0; j < 8; ++j) o[j] = f2bf(s[j]);
        *(uint4*)&Xb[(size_t)idx * 8] = *(uint4*)o;
    }
}

// ---------------- Kernel G1: gating partial logits (fp32, deterministic) ----------------
__global__ __launch_bounds__(256) void gate_partial(
    const float* __restrict__ x, const float* __restrict__ es,
    float* __restrict__ gpart)               // [4][NTOK][32]
{
    const int n0    = blockIdx.x * 16;
    const int dbase = blockIdx.y * 256;
    const int tid   = threadIdx.x;

    __shared__ float smem[4608];             // staging tiles, reused as Lp
    float* Xt  = smem;                       // [d][tok] stride 36
    float* Est = smem + 64 * 36;             // [d][e]   stride 36

    const int t4  = (tid & 3) * 4;
    const int e4  = ((tid >> 2) & 7) * 4;
    const int rep = tid >> 5;

    const int xr = tid & 15, xc4 = (tid >> 4) * 4;
    const int er = tid & 31, ec8 = (tid >> 5) * 8;

    float acc[4][4] = {};

    for (int dc = dbase; dc < dbase + 256; dc += 64) {
        __syncthreads();
        {
            float4 v = *(const float4*)&x[(size_t)(n0 + xr) * DDIM + dc + xc4];
            Xt[(xc4 + 0) * 36 + xr] = v.x; Xt[(xc4 + 1) * 36 + xr] = v.y;
            Xt[(xc4 + 2) * 36 + xr] = v.z; Xt[(xc4 + 3) * 36 + xr] = v.w;
        }
        #pragma unroll
        for (int i = 0; i < 2; ++i) {
            float4 v = *(const float4*)&es[(size_t)er * DDIM + dc + ec8 + i * 4];
            Est[(ec8 + i * 4 + 0) * 36 + er] = v.x;
            Est[(ec8 + i * 4 + 1) * 36 + er] = v.y;
            Est[(ec8 + i * 4 + 2) * 36 + er] = v.z;
            Est[(ec8 + i * 4 + 3) * 36 + er] = v.w;
        }
        __syncthreads();

        #pragma unroll
        for (int s = 0; s < 8; ++s) {
            int d = s * 8 + rep;
            float4 xv = *(const float4*)&Xt[d * 36 + t4];
            float4 ev = *(const float4*)&Est[d * 36 + e4];
            const float xa[4] = {xv.x, xv.y, xv.z, xv.w};
            const float ea[4] = {ev.x, ev.y, ev.z, ev.w};
            #pragma unroll
            for (int i = 0; i < 4; ++i)
                #pragma unroll
                for (int j = 0; j < 4; ++j)
                    acc[i][j] = fmaf(xa[i], ea[j], acc[i][j]);
        }
    }

    __syncthreads();
    float* Lp = smem;                         // [rep 8][tok 16][e 33]
    #pragma unroll
    for (int i = 0; i < 4; ++i)
        #pragma unroll
        for (int j = 0; j < 4; ++j)
            Lp[(rep * 16 + t4 + i) * 33 + e4 + j] = acc[i][j];
    __syncthreads();

    for (int p = tid; p < 16 * 32; p += 256) {
        int tok = p >> 5, e = p & 31;
        float s = 0.f;
        #pragma unroll
        for (int r = 0; r < 8; ++r) s += Lp[(r * 16 + tok) * 33 + e];
        gpart[((size_t)blockIdx.y * NTOK + n0 + tok) * NEXP + e] = s;
    }
}

// ---------------- Kernel G2: sum partials, top-4 (registers), scatter ----------------
__global__ __launch_bounds__(256) void topk_scatter(
    const float* __restrict__ gpart,
    int* __restrict__ cnt, int* __restrict__ tok_list, float* __restrict__ gates)
{
    const int tid = threadIdx.x;
    const int n   = blockIdx.x * 256 + tid;

    __shared__ int hist[NEXP];
    __shared__ int bbase[NEXP];
    if (tid < NEXP) hist[tid] = 0;

    float lg[NEXP];
    #pragma unroll
    for (int i = 0; i < 8; ++i) {
        float4 v = *(const float4*)&gpart[(size_t)n * NEXP + i * 4];
        lg[i*4+0] = v.x; lg[i*4+1] = v.y; lg[i*4+2] = v.z; lg[i*4+3] = v.w;
    }
    #pragma unroll
    for (int j = 1; j < 4; ++j)
        #pragma unroll
        for (int i = 0; i < 8; ++i) {
            float4 v = *(const float4*)&gpart[((size_t)j * NTOK + n) * NEXP + i * 4];
            lg[i*4+0] += v.x; lg[i*4+1] += v.y; lg[i*4+2] += v.z; lg[i*4+3] += v.w;
        }

    int sel[TOPK]; float sv[TOPK];
    #pragma unroll
    for (int j = 0; j < TOPK; ++j) {
        float bv = -3.0e38f; int bi = 0;
        #pragma unroll
        for (int e = 0; e < NEXP; ++e) {
            bool taken = false;
            #pragma unroll
            for (int q = 0; q < j; ++q) taken = taken || (sel[q] == e);
            float v = taken ? -3.0e38f : lg[e];
            if (v > bv) { bv = v; bi = e; }   // strict >: lowest idx wins ties
        }
        sel[j] = bi; sv[j] = bv;
    }

    __syncthreads();
    int lpos[TOPK];
    #pragma unroll
    for (int j = 0; j < TOPK; ++j) {
        gates[n * TOPK + j] = 1.f / (1.f + expf(-sv[j]));
        lpos[j] = atomicAdd(&hist[sel[j]], 1);
    }
    __syncthreads();
    if (tid < NEXP) bbase[tid] = atomicAdd(&cnt[tid], hist[tid]);
    __syncthreads();
    #pragma unroll
    for (int j = 0; j < TOPK; ++j)
        tok_list[(size_t)sel[j] * NTOK + bbase[sel[j]] + lpos[j]] = n * TOPK + j;
}

// ---------------- Kernel F: fused expert FFN ----------------
// 1-D grid, bid -> (e = bid&31, tile = bid>>5): all tiles of expert e share bid%8,
// i.e. one XCD under round-robin dispatch -> K_e/V_e stay in that XCD's L2.
// Phase A: H = relu(X@K_e)*g into LDS.  Phase B: Ob = H @ V_e, V streamed through
// the same 16 KB buffer; C-tile bounced through LDS for coalesced uint4 stores.
__global__ __launch_bounds__(256) void ffn_fused(
    const unsigned short* __restrict__ Xb,   // [N][1024] bf16
    const unsigned short* __restrict__ Kb,   // [E][128][128][8]
    const unsigned short* __restrict__ Vb,   // [E][16][1024][8]
    const int* __restrict__ cnt, const int* __restrict__ tok_list,
    const float* __restrict__ gates,
    unsigned short* __restrict__ Ob)         // [N*4][1024] bf16
{
    const int bid = blockIdx.x;
    const int e = bid & 31, tile = bid >> 5;
    const int c = cnt[e], base = tile * 32;
    if (base >= c) return;
    const int nt   = min(32, c - base);
    const int tid  = threadIdx.x, wave = tid >> 6, lane = tid & 63;
    const int lm   = lane & 15, quad = lane >> 4;
    const int r2   = (wave >> 1) * 16;       // 16-row half of the 32-slot tile
    const int c2   = (wave & 1) * 64;        // phase A: 64-col half of 128
    const int cw   = (wave & 1) * 32;        // phase B: 32-col half of 64

    __shared__ __align__(16) unsigned short KV[8192];     // 16 KB: Ks[8][128][8] | Vs[16][64][8]
    __shared__ __align__(16) unsigned short XO[2304];     // 4.6 KB: phase A Xs[8][32][8] | phase B OSB[32][72]
    __shared__ __align__(16) unsigned short Hs[32 * 136]; // 8.7 KB row-major, pad 136
    __shared__ int slot[32]; __shared__ int gtok[32]; __shared__ float gs[32];

    if (tid < 32) {
        if (tid < nt) {
            int v = tok_list[(size_t)e * NTOK + base + tid];
            slot[tid] = v; gtok[tid] = v >> 2; gs[tid] = gates[v];
        } else { slot[tid] = -1; gtok[tid] = 0; gs[tid] = 0.f; }
    }
    __syncthreads();

    const unsigned short* Ke   = Kb + (size_t)e * 131072;
    const unsigned short* Ve   = Vb + (size_t)e * 131072;
    const unsigned short* xrow = Xb + (size_t)gtok[lane & 31] * DDIM + (lane >> 5) * 8;

    // ---------------- phase A: H[32][128] = X_tile @ K_e ----------------
    f32x4 acc[4];
    #pragma unroll
    for (int j = 0; j < 4; ++j) acc[j] = (f32x4){0.f, 0.f, 0.f, 0.f};

    auto stageA = [&](int t) {
        int dc = t * 64;
        #pragma unroll
        for (int i = 0; i < 4; ++i) {          // K: 16 x 1KB pieces, 4/wave
            int p = wave * 4 + i;
            async_cp16(Ke + ((size_t)(dc / 8 + (p >> 1)) * 128 + (p & 1) * 64 + lane) * 8,
                       &KV[p * 512]);
        }
        if (wave == 0) {                        // X: 4 x 1KB pieces (row gather)
            #pragma unroll
            for (int p = 0; p < 4; ++p)
                async_cp16(xrow + dc + p * 16, &XO[p * 512]);
        }
    };

    stageA(0);
    __syncthreads();                           // drain

    for (int t = 0; t < 16; ++t) {
        #pragma unroll
        for (int ks = 0; ks < 2; ++ks) {
            int k0 = ks * 4 + quad;
            bf16x8 a = *(const bf16x8*)&XO[(k0 * 32 + r2 + lm) * 8];
            #pragma unroll
            for (int tj = 0; tj < 4; ++tj) {
                bf16x8 bb = *(const bf16x8*)&KV[(k0 * 128 + c2 + tj * 16 + lm) * 8];
                acc[tj] = __builtin_amdgcn_mfma_f32_16x16x32_bf16(a, bb, acc[tj], 0, 0, 0);
            }
        }
        if (t < 15) {
            __syncthreads();                   // all reads of chunk t done
            stageA(t + 1);
            __syncthreads();                   // drain chunk t+1
        }
    }

    // epilogue A: relu * gate -> Hs (row-major [m][136])
    #pragma unroll
    for (int reg = 0; reg < 4; ++reg) {
        int m = r2 + quad * 4 + reg;
        float g = gs[m];
        #pragma unroll
        for (int tj = 0; tj < 4; ++tj)
            Hs[m * 136 + c2 + tj * 16 + lm] = f2bf(fmaxf(acc[tj][reg], 0.f) * g);
    }
    __syncthreads();                           // Hs complete; KV/XO phase-A reads done

    // ---------------- phase B: Ob = H @ V_e ----------------
    auto stageV = [&](int cc) {
        #pragma unroll
        for (int i = 0; i < 4; ++i) {          // V: 16 x 1KB pieces, 4/wave
            int p = wave * 4 + i;
            async_cp16(Ve + ((size_t)p * 1024 + cc * 64 + lane) * 8, &KV[p * 512]);
        }
    };

    stageV(0);
    __syncthreads();                           // drain

    const int om = tid >> 3, oseg = tid & 7;   // store mapping: 1 uint4/thread
    const int os = slot[om];

    for (int cc = 0; cc < 16; ++cc) {
        f32x4 acc2[2];
        acc2[0] = (f32x4){0.f, 0.f, 0.f, 0.f};
        acc2[1] = (f32x4){0.f, 0.f, 0.f, 0.f};

        #pragma unroll
        for (int ks = 0; ks < 4; ++ks) {
            int k0 = ks * 4 + quad;
            bf16x8 a = *(const bf16x8*)&Hs[(r2 + lm) * 136 + k0 * 8];
            #pragma unroll
            for (int tj = 0; tj < 2; ++tj) {
                bf16x8 bb = *(const bf16x8*)&KV[(k0 * 64 + cw + tj * 16 + lm) * 8];
                acc2[tj] = __builtin_amdgcn_mfma_f32_16x16x32_bf16(a, bb, acc2[tj], 0, 0, 0);
            }
        }

        // bounce C-tile through LDS (OSB[32][72], 16B-aligned rows) for vector stores
        #pragma unroll
        for (int reg = 0; reg < 4; ++reg) {
            int m = r2 + quad * 4 + reg;
            XO[m * 72 + cw + lm]      = f2bf(acc2[0][reg]);
            XO[m * 72 + cw + 16 + lm] = f2bf(acc2[1][reg]);
        }
        __syncthreads();                       // OSB complete; KV reads done

        if (os >= 0) {
            uint4 v = *(const uint4*)&XO[om * 72 + oseg * 8];
            *(uint4*)&Ob[(size_t)os * DDIM + cc * 64 + oseg * 8] = v;
        }
        if (cc < 15) stageV(cc + 1);
        __syncthreads();                       // drain async; OSB reads done
    }
}

// ---------------- Kernel R: out[n] = sum_j Ob[4n+j]  (bf16 -> fp32) ----------------
__global__ __launch_bounds__(256) void reduce_out(
    const unsigned short* __restrict__ Ob, float* __restrict__ out)
{
    const int tid = threadIdx.x;
    const int n   = blockIdx.x * 2 + (tid >> 7);
    const int cc  = (tid & 127) * 8;

    float s[8] = {};
    #pragma unroll
    for (int j = 0; j < 4; ++j) {
        uint4 v = *(const uint4*)&Ob[((size_t)n * 4 + j) * DDIM + cc];
        const unsigned int w[4] = {v.x, v.y, v.z, v.w};
        #pragma unroll
        for (int q = 0; q < 4; ++q) {
            s[q * 2 + 0] += bf2f((unsigned short)(w[q] & 0xffff));
            s[q * 2 + 1] += bf2f((unsigned short)(w[q] >> 16));
        }
    }
    float4 o0 = {s[0], s[1], s[2], s[3]};
    float4 o1 = {s[4], s[5], s[6], s[7]};
    *(float4*)&out[(size_t)n * DDIM + cc]     = o0;
    *(float4*)&out[(size_t)n * DDIM + cc + 4] = o1;
}

extern "C" void kernel_launch(void* const* d_in, const int* in_sizes, int n_in,
                              void* d_out, int out_size, void* d_ws, size_t ws_size,
                              hipStream_t stream) {
    const float* x      = (const float*)d_in[0];
    const float* es     = (const float*)d_in[1];
    const float* keys   = (const float*)d_in[2];
    const float* values = (const float*)d_in[3];
    float* out          = (float*)d_out;

    // workspace layout (~105 MB)
    char* w = (char*)d_ws;
    int*   cnt      = (int*)w;               w += 256;
    int*   tok_list = (int*)w;               w += (size_t)NEXP * NTOK * sizeof(int);    // 1 MB
    float* gates    = (float*)w;             w += (size_t)NTOK * TOPK * sizeof(float);  // 128 KB
    float* gpart    = (float*)w;             w += (size_t)4 * NTOK * NEXP * sizeof(float); // 4 MB
    unsigned short* Kb = (unsigned short*)w; w += (size_t)NEXP * 128 * 128 * 8 * 2;     // 8 MB
    unsigned short* Vb = (unsigned short*)w; w += (size_t)NEXP * 16 * 1024 * 8 * 2;     // 8 MB
    unsigned short* Xb = (unsigned short*)w; w += (size_t)NTOK * DDIM * 2;              // 16.8 MB
    unsigned short* Ob = (unsigned short*)w;                                            // 67 MB

    hipMemsetAsync(cnt, 0, NEXP * sizeof(int), stream);

    prep_weights<<<8192, 256, 0, stream>>>(x, keys, values, Kb, Vb, Xb);
    gate_partial<<<dim3(NTOK / 16, 4), 256, 0, stream>>>(x, es, gpart);
    topk_scatter<<<NTOK / 256, 256, 0, stream>>>(gpart, cnt, tok_list, gates);

    ffn_fused<<<128 * NEXP, 256, 0, stream>>>(Xb, Kb, Vb, cnt, tok_list, gates, Ob);
    reduce_out<<<NTOK / 2, 256, 0, stream>>>(Ob, out);
}

// Round 12
// 201.319 us; speedup vs baseline: 1.1192x; 1.0135x over previous
//
#include <hip/hip_runtime.h>
#include <hip/hip_bf16.h>

#define NTOK 8192   // B*S
#define DDIM 1024
#define NEXP 32
#define HDIM 128
#define TOPK 4

typedef __attribute__((ext_vector_type(8))) short bf16x8;
typedef __attribute__((ext_vector_type(4))) float f32x4;

typedef unsigned int uint_g __attribute__((address_space(1)));
typedef unsigned int uint_l __attribute__((address_space(3)));

// async 16B/lane global->LDS; LDS dest = wave-uniform base + lane*16.
// Global source may be per-lane (gather is legal; only the LDS side is constrained).
__device__ __forceinline__ void async_cp16(const void* g, void* l) {
    __builtin_amdgcn_global_load_lds((const uint_g*)g, (uint_l*)l, 16, 0, 0);
}

__device__ inline unsigned short f2bf(float f) {
    unsigned int u = __builtin_bit_cast(unsigned int, f);
    unsigned int r = (u + 0x7fffu + ((u >> 16) & 1u)) >> 16;   // RNE
    return (unsigned short)r;
}
__device__ inline float bf2f(unsigned short s) {
    unsigned int u = ((unsigned int)s) << 16;
    return __builtin_bit_cast(float, u);
}

// ---------------- Kernel P: K/V -> bf16 MFMA-B layout; X -> bf16 row-major ----------------
__global__ __launch_bounds__(256) void prep_weights(
    const float* __restrict__ x,
    const float* __restrict__ keys, const float* __restrict__ values,
    unsigned short* __restrict__ Kb, unsigned short* __restrict__ Vb,
    unsigned short* __restrict__ Xb)
{
    int idx = blockIdx.x * 256 + threadIdx.x;
    unsigned short o[8];
    if (idx < NEXP * 128 * 128) {            // keys: (e, k0 [128], n [128])
        int n = idx & 127, k0 = (idx >> 7) & 127, e = idx >> 14;
        const float* s = keys + ((size_t)e * DDIM + k0 * 8) * HDIM + n;
        #pragma unroll
        for (int j = 0; j < 8; ++j) o[j] = f2bf(s[(size_t)j * HDIM]);
        *(uint4*)&Kb[(size_t)idx * 8] = *(uint4*)o;
    } else if (idx < 2 * NEXP * 128 * 128) { // values: (e, k0 [16], n [1024])
        idx -= NEXP * 128 * 128;
        int n = idx & 1023, k0 = (idx >> 10) & 15, e = idx >> 14;
        const float* s = values + ((size_t)e * HDIM + k0 * 8) * DDIM + n;
        #pragma unroll
        for (int j = 0; j < 8; ++j) o[j] = f2bf(s[(size_t)j * DDIM]);
        *(uint4*)&Vb[(size_t)idx * 8] = *(uint4*)o;
    } else {                                 // x: 8 contiguous elements / thread
        idx -= 2 * NEXP * 128 * 128;
        const float* s = x + (size_t)idx * 8;
        #pragma unroll
        for (int j = 0; j < 8; ++j) o[j] = f2bf(s[j]);
        *(uint4*)&Xb[(size_t)idx * 8] = *(uint4*)o;
    }
}

// ---------------- Kernel G1: gating partial logits (fp32, deterministic) ----------------
__global__ __launch_bounds__(256) void gate_partial(
    const float* __restrict__ x, const float* __restrict__ es,
    float* __restrict__ gpart)               // [4][NTOK][32]
{
    const int n0    = blockIdx.x * 16;
    const int dbase = blockIdx.y * 256;
    const int tid   = threadIdx.x;

    __shared__ float smem[4608];             // staging tiles, reused as Lp
    float* Xt  = smem;                       // [d][tok] stride 36
    float* Est = smem + 64 * 36;             // [d][e]   stride 36

    const int t4  = (tid & 3) * 4;
    const int e4  = ((tid >> 2) & 7) * 4;
    const int rep = tid >> 5;

    const int xr = tid & 15, xc4 = (tid >> 4) * 4;
    const int er = tid & 31, ec8 = (tid >> 5) * 8;

    float acc[4][4] = {};

    for (int dc = dbase; dc < dbase + 256; dc += 64) {
        __syncthreads();
        {
            float4 v = *(const float4*)&x[(size_t)(n0 + xr) * DDIM + dc + xc4];
            Xt[(xc4 + 0) * 36 + xr] = v.x; Xt[(xc4 + 1) * 36 + xr] = v.y;
            Xt[(xc4 + 2) * 36 + xr] = v.z; Xt[(xc4 + 3) * 36 + xr] = v.w;
        }
        #pragma unroll
        for (int i = 0; i < 2; ++i) {
            float4 v = *(const float4*)&es[(size_t)er * DDIM + dc + ec8 + i * 4];
            Est[(ec8 + i * 4 + 0) * 36 + er] = v.x;
            Est[(ec8 + i * 4 + 1) * 36 + er] = v.y;
            Est[(ec8 + i * 4 + 2) * 36 + er] = v.z;
            Est[(ec8 + i * 4 + 3) * 36 + er] = v.w;
        }
        __syncthreads();

        #pragma unroll
        for (int s = 0; s < 8; ++s) {
            int d = s * 8 + rep;
            float4 xv = *(const float4*)&Xt[d * 36 + t4];
            float4 ev = *(const float4*)&Est[d * 36 + e4];
            const float xa[4] = {xv.x, xv.y, xv.z, xv.w};
            const float ea[4] = {ev.x, ev.y, ev.z, ev.w};
            #pragma unroll
            for (int i = 0; i < 4; ++i)
                #pragma unroll
                for (int j = 0; j < 4; ++j)
                    acc[i][j] = fmaf(xa[i], ea[j], acc[i][j]);
        }
    }

    __syncthreads();
    float* Lp = smem;                         // [rep 8][tok 16][e 33]
    #pragma unroll
    for (int i = 0; i < 4; ++i)
        #pragma unroll
        for (int j = 0; j < 4; ++j)
            Lp[(rep * 16 + t4 + i) * 33 + e4 + j] = acc[i][j];
    __syncthreads();

    for (int p = tid; p < 16 * 32; p += 256) {
        int tok = p >> 5, e = p & 31;
        float s = 0.f;
        #pragma unroll
        for (int r = 0; r < 8; ++r) s += Lp[(r * 16 + tok) * 33 + e];
        gpart[((size_t)blockIdx.y * NTOK + n0 + tok) * NEXP + e] = s;
    }
}

// ---------------- Kernel G2: sum partials, top-4 (registers), scatter ----------------
__global__ __launch_bounds__(256) void topk_scatter(
    const float* __restrict__ gpart,
    int* __restrict__ cnt, int* __restrict__ tok_list, float* __restrict__ gates)
{
    const int tid = threadIdx.x;
    const int n   = blockIdx.x * 256 + tid;

    __shared__ int hist[NEXP];
    __shared__ int bbase[NEXP];
    if (tid < NEXP) hist[tid] = 0;

    float lg[NEXP];
    #pragma unroll
    for (int i = 0; i < 8; ++i) {
        float4 v = *(const float4*)&gpart[(size_t)n * NEXP + i * 4];
        lg[i*4+0] = v.x; lg[i*4+1] = v.y; lg[i*4+2] = v.z; lg[i*4+3] = v.w;
    }
    #pragma unroll
    for (int j = 1; j < 4; ++j)
        #pragma unroll
        for (int i = 0; i < 8; ++i) {
            float4 v = *(const float4*)&gpart[((size_t)j * NTOK + n) * NEXP + i * 4];
            lg[i*4+0] += v.x; lg[i*4+1] += v.y; lg[i*4+2] += v.z; lg[i*4+3] += v.w;
        }

    int sel[TOPK]; float sv[TOPK];
    #pragma unroll
    for (int j = 0; j < TOPK; ++j) {
        float bv = -3.0e38f; int bi = 0;
        #pragma unroll
        for (int e = 0; e < NEXP; ++e) {
            bool taken = false;
            #pragma unroll
            for (int q = 0; q < j; ++q) taken = taken || (sel[q] == e);
            float v = taken ? -3.0e38f : lg[e];
            if (v > bv) { bv = v; bi = e; }   // strict >: lowest idx wins ties
        }
        sel[j] = bi; sv[j] = bv;
    }

    __syncthreads();
    int lpos[TOPK];
    #pragma unroll
    for (int j = 0; j < TOPK; ++j) {
        gates[n * TOPK + j] = 1.f / (1.f + expf(-sv[j]));
        lpos[j] = atomicAdd(&hist[sel[j]], 1);
    }
    __syncthreads();
    if (tid < NEXP) bbase[tid] = atomicAdd(&cnt[tid], hist[tid]);
    __syncthreads();
    #pragma unroll
    for (int j = 0; j < TOPK; ++j)
        tok_list[(size_t)sel[j] * NTOK + bbase[sel[j]] + lpos[j]] = n * TOPK + j;
}

// ---------------- Kernel F: fused expert FFN, 64-slot tiles ----------------
// 1-D grid, bid -> (e = bid&31, tile = bid>>5): expert pinned to one XCD's L2.
// Phase A: H[64][128] = relu(X@K_e)*g into LDS (stride 140, 16-bank pattern).
// Phase B: Ob = H @ V_e, V streamed in 64-col chunks through the same 16 KB buffer;
// C-tile bounced through LDS for coalesced uint4 stores.  16 MFMA/wave per chunk.
__global__ __launch_bounds__(256) void ffn_fused(
    const unsigned short* __restrict__ Xb,   // [N][1024] bf16
    const unsigned short* __restrict__ Kb,   // [E][128][128][8]
    const unsigned short* __restrict__ Vb,   // [E][16][1024][8]
    const int* __restrict__ cnt, const int* __restrict__ tok_list,
    const float* __restrict__ gates,
    unsigned short* __restrict__ Ob)         // [N*4][1024] bf16
{
    const int bid = blockIdx.x;
    const int e = bid & 31, tile = bid >> 5;
    const int c = cnt[e], base = tile * 64;
    if (base >= c) return;
    const int nt   = min(64, c - base);
    const int tid  = threadIdx.x, wave = tid >> 6, lane = tid & 63;
    const int lm   = lane & 15, quad = lane >> 4;
    const int r2   = (wave >> 1) * 32;       // 32-row half of the 64-slot tile
    const int c2   = (wave & 1) * 64;        // phase A: 64-col half of 128
    const int cw   = (wave & 1) * 32;        // phase B: 32-col half of 64

    __shared__ __align__(16) unsigned short KV[8192];     // 16 KB: K[8][128][8] | V[16][64][8]
    __shared__ __align__(16) unsigned short XO[4608];     // 9.2 KB: A: Xs[8][64][8] | B: OSB[64][72]
    __shared__ __align__(16) unsigned short Hs[64 * 140]; // 17.9 KB (stride 140 -> 16 banks)
    __shared__ int slot[64]; __shared__ int gtok[64]; __shared__ float gs[64];

    if (tid < 64) {
        if (tid < nt) {
            int v = tok_list[(size_t)e * NTOK + base + tid];
            slot[tid] = v; gtok[tid] = v >> 2; gs[tid] = gates[v];
        } else { slot[tid] = -1; gtok[tid] = 0; gs[tid] = 0.f; }
    }
    __syncthreads();

    const unsigned short* Ke    = Kb + (size_t)e * 131072;
    const unsigned short* Ve    = Vb + (size_t)e * 131072;
    const unsigned short* xrowb = Xb + (size_t)gtok[lane] * DDIM;   // per-lane token row

    // ---------------- phase A: H[64][128] = X_tile @ K_e ----------------
    f32x4 acc[2][4];
    #pragma unroll
    for (int i = 0; i < 2; ++i)
        #pragma unroll
        for (int j = 0; j < 4; ++j) acc[i][j] = (f32x4){0.f, 0.f, 0.f, 0.f};

    auto stageA = [&](int t) {
        int dc = t * 64;
        #pragma unroll
        for (int i = 0; i < 4; ++i) {          // K: 16 x 1KB pieces, 4/wave
            int p = wave * 4 + i;
            async_cp16(Ke + ((size_t)(dc / 8 + (p >> 1)) * 128 + (p & 1) * 64 + lane) * 8,
                       &KV[p * 512]);
        }
        #pragma unroll
        for (int i = 0; i < 2; ++i) {          // X: 8 x 1KB pieces (row gather), 2/wave
            int k0 = wave * 2 + i;
            async_cp16(xrowb + dc + k0 * 8, &XO[k0 * 512]);
        }
    };

    stageA(0);
    __syncthreads();                           // drain

    for (int t = 0; t < 16; ++t) {
        #pragma unroll
        for (int ks = 0; ks < 2; ++ks) {
            int k0 = ks * 4 + quad;
            bf16x8 a0 = *(const bf16x8*)&XO[(k0 * 64 + r2 + lm) * 8];
            bf16x8 a1 = *(const bf16x8*)&XO[(k0 * 64 + r2 + 16 + lm) * 8];
            #pragma unroll
            for (int tj = 0; tj < 4; ++tj) {
                bf16x8 bb = *(const bf16x8*)&KV[(k0 * 128 + c2 + tj * 16 + lm) * 8];
                acc[0][tj] = __builtin_amdgcn_mfma_f32_16x16x32_bf16(a0, bb, acc[0][tj], 0, 0, 0);
                acc[1][tj] = __builtin_amdgcn_mfma_f32_16x16x32_bf16(a1, bb, acc[1][tj], 0, 0, 0);
            }
        }
        if (t < 15) {
            __syncthreads();                   // all reads of chunk t done
            stageA(t + 1);
            __syncthreads();                   // drain chunk t+1
        }
    }

    // epilogue A: relu * gate -> Hs (row-major [m][140])
    #pragma unroll
    for (int ti = 0; ti < 2; ++ti)
        #pragma unroll
        for (int reg = 0; reg < 4; ++reg) {
            int m = r2 + ti * 16 + quad * 4 + reg;
            float g = gs[m];
            #pragma unroll
            for (int tj = 0; tj < 4; ++tj)
                Hs[m * 140 + c2 + tj * 16 + lm] = f2bf(fmaxf(acc[ti][tj][reg], 0.f) * g);
        }
    __syncthreads();                           // Hs complete; KV/XO phase-A reads done

    // ---------------- phase B: Ob = H @ V_e ----------------
    auto stageV = [&](int cc) {
        #pragma unroll
        for (int i = 0; i < 4; ++i) {          // V: 16 x 1KB pieces, 4/wave
            int p = wave * 4 + i;
            async_cp16(Ve + ((size_t)p * 1024 + cc * 64 + lane) * 8, &KV[p * 512]);
        }
    };

    stageV(0);
    __syncthreads();                           // drain

    const int om = tid >> 2, oq = tid & 3;     // store mapping: 2 uint4/thread
    const int os = slot[om];

    for (int cc = 0; cc < 16; ++cc) {
        f32x4 acc2[2][2];
        #pragma unroll
        for (int i = 0; i < 2; ++i) {
            acc2[i][0] = (f32x4){0.f, 0.f, 0.f, 0.f};
            acc2[i][1] = (f32x4){0.f, 0.f, 0.f, 0.f};
        }

        #pragma unroll
        for (int ks = 0; ks < 4; ++ks) {
            int k0 = ks * 4 + quad;
            bf16x8 a0 = *(const bf16x8*)&Hs[(r2 + lm) * 140 + k0 * 8];
            bf16x8 a1 = *(const bf16x8*)&Hs[(r2 + 16 + lm) * 140 + k0 * 8];
            #pragma unroll
            for (int tj = 0; tj < 2; ++tj) {
                bf16x8 bb = *(const bf16x8*)&KV[(k0 * 64 + cw + tj * 16 + lm) * 8];
                acc2[0][tj] = __builtin_amdgcn_mfma_f32_16x16x32_bf16(a0, bb, acc2[0][tj], 0, 0, 0);
                acc2[1][tj] = __builtin_amdgcn_mfma_f32_16x16x32_bf16(a1, bb, acc2[1][tj], 0, 0, 0);
            }
        }

        // bounce C-tile through LDS (OSB[64][72]) for coalesced 16B stores
        #pragma unroll
        for (int ti = 0; ti < 2; ++ti)
            #pragma unroll
            for (int reg = 0; reg < 4; ++reg) {
                int m = r2 + ti * 16 + quad * 4 + reg;
                XO[m * 72 + cw + lm]      = f2bf(acc2[ti][0][reg]);
                XO[m * 72 + cw + 16 + lm] = f2bf(acc2[ti][1][reg]);
            }
        __syncthreads();                       // OSB complete; KV reads done

        if (os >= 0) {
            uint4 v0 = *(const uint4*)&XO[om * 72 + oq * 16];
            uint4 v1 = *(const uint4*)&XO[om * 72 + oq * 16 + 8];
            unsigned short* op = Ob + (size_t)os * DDIM + cc * 64 + oq * 16;
            *(uint4*)op       = v0;
            *(uint4*)(op + 8) = v1;
        }
        if (cc < 15) stageV(cc + 1);
        __syncthreads();                       // drain async; OSB reads done
    }
}

// ---------------- Kernel R: out[n] = sum_j Ob[4n+j]  (bf16 -> fp32) ----------------
__global__ __launch_bounds__(256) void reduce_out(
    const unsigned short* __restrict__ Ob, float* __restrict__ out)
{
    const int tid = threadIdx.x;
    const int n   = blockIdx.x * 2 + (tid >> 7);
    const int cc  = (tid & 127) * 8;

    float s[8] = {};
    #pragma unroll
    for (int j = 0; j < 4; ++j) {
        uint4 v = *(const uint4*)&Ob[((size_t)n * 4 + j) * DDIM + cc];
        const unsigned int w[4] = {v.x, v.y, v.z, v.w};
        #pragma unroll
        for (int q = 0; q < 4; ++q) {
            s[q * 2 + 0] += bf2f((unsigned short)(w[q] & 0xffff));
            s[q * 2 + 1] += bf2f((unsigned short)(w[q] >> 16));
        }
    }
    float4 o0 = {s[0], s[1], s[2], s[3]};
    float4 o1 = {s[4], s[5], s[6], s[7]};
    *(float4*)&out[(size_t)n * DDIM + cc]     = o0;
    *(float4*)&out[(size_t)n * DDIM + cc + 4] = o1;
}

extern "C" void kernel_launch(void* const* d_in, const int* in_sizes, int n_in,
                              void* d_out, int out_size, void* d_ws, size_t ws_size,
                              hipStream_t stream) {
    const float* x      = (const float*)d_in[0];
    const float* es     = (const float*)d_in[1];
    const float* keys   = (const float*)d_in[2];
    const float* values = (const float*)d_in[3];
    float* out          = (float*)d_out;

    // workspace layout (~105 MB)
    char* w = (char*)d_ws;
    int*   cnt      = (int*)w;               w += 256;
    int*   tok_list = (int*)w;               w += (size_t)NEXP * NTOK * sizeof(int);    // 1 MB
    float* gates    = (float*)w;             w += (size_t)NTOK * TOPK * sizeof(float);  // 128 KB
    float* gpart    = (float*)w;             w += (size_t)4 * NTOK * NEXP * sizeof(float); // 4 MB
    unsigned short* Kb = (unsigned short*)w; w += (size_t)NEXP * 128 * 128 * 8 * 2;     // 8 MB
    unsigned short* Vb = (unsigned short*)w; w += (size_t)NEXP * 16 * 1024 * 8 * 2;     // 8 MB
    unsigned short* Xb = (unsigned short*)w; w += (size_t)NTOK * DDIM * 2;              // 16.8 MB
    unsigned short* Ob = (unsigned short*)w;                                            // 67 MB

    hipMemsetAsync(cnt, 0, NEXP * sizeof(int), stream);

    prep_weights<<<8192, 256, 0, stream>>>(x, keys, values, Kb, Vb, Xb);
    gate_partial<<<dim3(NTOK / 16, 4), 256, 0, stream>>>(x, es, gpart);
    topk_scatter<<<NTOK / 256, 256, 0, stream>>>(gpart, cnt, tok_list, gates);

    ffn_fused<<<128 * NEXP, 256, 0, stream>>>(Xb, Kb, Vb, cnt, tok_list, gates, Ob);
    reduce_out<<<NTOK / 2, 256, 0, stream>>>(Ob, out);
}